// Round 1
// baseline (440.850 us; speedup 1.0000x reference)
//
#include <hip/hip_runtime.h>
#include <stdint.h>
#include <stddef.h>

// ============================================================================
// MHA block on gfx950, bf16 MFMA pipeline.
// Shapes: B=2, S=2048, D=1024, H=16, hd=64.  BH = 32, M = B*S = 4096.
// Stages:
//   1. cast x, wq, wk, wv, wo  f32 -> bf16  (wq/wk/wv stacked into one [3072][1024])
//   2. qkv_gemm: [4096,3072] = x @ Wqkv^T + bias; writes q,k -> (bh, s, d) bf16,
//      v -> transposed (bh, d, s) bf16 so flash PV fragments read contiguously.
//   3. rope on q,k in place (interleaved pairs).
//   4. flash attention: per (bh, 128-row q-block), 64-wide kv tiles, online softmax.
//      Output o_bf (b, s, h*64+d) bf16.
//   5. oproj_gemm: out = o_bf @ wo^T + bias, fp32 -> d_out.
// MFMA layouts (verified per guide m89/m91/m120):
//   A-frag:  A[m = lane&15][k = (lane>>4)*8 + j]   (8 contiguous bf16 = 16B/lane)
//   B-frag:  B[k = (lane>>4)*8 + j][n = lane&15]  == row-major read of B^T tile
//   C/D:     col = lane&15, row = (lane>>4)*4 + reg
// GEMM LDS is "fragment-major": 16B chunk index ((row>>4)*4 + kchunk)*16 + (row&15),
// so wave reads are lane-contiguous 1KB blocks -> zero bank conflicts, and staging
// stores are lane-contiguous too (also makes a later global_load_lds swap trivial).
// ============================================================================

typedef __bf16 bf16x8 __attribute__((ext_vector_type(8)));
typedef float  f32x4  __attribute__((ext_vector_type(4)));

__device__ __forceinline__ unsigned short f2b(float f) {
  union { float f; uint32_t u; } v; v.f = f;
  uint32_t u = v.u;
  return (unsigned short)((u + 0x7FFFu + ((u >> 16) & 1u)) >> 16);  // RNE
}
__device__ __forceinline__ float b2f(unsigned short s) {
  union { uint32_t u; float f; } v; v.u = ((uint32_t)s) << 16;
  return v.f;
}

// ---------------- cast f32 -> bf16, 4 elems/thread ----------------
__global__ void cast_kernel(const float* __restrict__ in,
                            unsigned short* __restrict__ out, int n4) {
  int i = blockIdx.x * blockDim.x + threadIdx.x;
  if (i >= n4) return;
  float4 v = ((const float4*)in)[i];
  ushort4 o;
  o.x = f2b(v.x); o.y = f2b(v.y); o.z = f2b(v.z); o.w = f2b(v.w);
  ((ushort4*)out)[i] = o;
}

// ---------------- fused QKV projection GEMM ----------------
// C[4096,3072] = Xbf[4096,1024] @ Wqkv[3072,1024]^T  (+bias), 128x128x32 tiles.
__global__ __launch_bounds__(256) void qkv_gemm_kernel(
    const unsigned short* __restrict__ A,    // x_bf [4096][1024]
    const unsigned short* __restrict__ W,    // wqkv [3072][1024]
    const float* __restrict__ biasq, const float* __restrict__ biask,
    const float* __restrict__ biasv,
    unsigned short* __restrict__ qo,         // [32][2048][64]
    unsigned short* __restrict__ ko,         // [32][2048][64]
    unsigned short* __restrict__ vto)        // [32][64][2048]  (transposed)
{
  __shared__ unsigned short As[128 * 32];
  __shared__ unsigned short Bs[128 * 32];
  const int tid  = threadIdx.x;
  const int w    = tid >> 6, l = tid & 63;
  const int lm   = l & 15,  quad = l >> 4;
  const int nblk = blockIdx.x;               // 0..23
  const int m0   = blockIdx.y * 128;
  const int n0g  = nblk * 128;               // row into stacked [3072] weights
  const int wm   = (w >> 1) * 64, wn = (w & 1) * 64;

  const f32x4 fzero = {0.f, 0.f, 0.f, 0.f};
  f32x4 acc[4][4];
#pragma unroll
  for (int i = 0; i < 4; ++i)
#pragma unroll
    for (int j = 0; j < 4; ++j) acc[i][j] = fzero;

  const int rowS = w * 16 + lm;              // staging row (+p*64), kchunk = quad
  for (int k0 = 0; k0 < 1024; k0 += 32) {
    uint4 ra[2], rb[2];
#pragma unroll
    for (int p = 0; p < 2; ++p) {
      const int row = rowS + p * 64;
      ra[p] = *(const uint4*)(A + (size_t)(m0 + row) * 1024 + k0 + quad * 8);
      rb[p] = *(const uint4*)(W + (size_t)(n0g + row) * 1024 + k0 + quad * 8);
    }
    __syncthreads();
#pragma unroll
    for (int p = 0; p < 2; ++p) {            // fragment-major chunk = w*64 + l + p*256
      *(uint4*)(As + (size_t)(w * 64 + l + p * 256) * 8) = ra[p];
      *(uint4*)(Bs + (size_t)(w * 64 + l + p * 256) * 8) = rb[p];
    }
    __syncthreads();
    bf16x8 af[4], bfc[4];
#pragma unroll
    for (int i = 0; i < 4; ++i)
      af[i] = *(const bf16x8*)(As + (size_t)((((w >> 1) * 4 + i) * 64 + l)) * 8);
#pragma unroll
    for (int j = 0; j < 4; ++j)
      bfc[j] = *(const bf16x8*)(Bs + (size_t)((((w & 1) * 4 + j) * 64 + l)) * 8);
#pragma unroll
    for (int i = 0; i < 4; ++i)
#pragma unroll
      for (int j = 0; j < 4; ++j)
        acc[i][j] = __builtin_amdgcn_mfma_f32_16x16x32_bf16(af[i], bfc[j], acc[i][j], 0, 0, 0);
  }

  const int which = nblk >> 3;               // 0=q 1=k 2=v
  const int n0    = (nblk & 7) * 128;        // col within 1024
  const float* bias = (which == 0) ? biasq : (which == 1) ? biask : biasv;
#pragma unroll
  for (int i = 0; i < 4; ++i) {
#pragma unroll
    for (int j = 0; j < 4; ++j) {
      const int n = n0 + wn + j * 16 + lm;
      const float bval = bias[n];
      const int h = n >> 6, d = n & 63;
#pragma unroll
      for (int r = 0; r < 4; ++r) {
        const int m = m0 + wm + i * 16 + quad * 4 + r;
        const int b = m >> 11, s = m & 2047;
        const unsigned short o = f2b(acc[i][j][r] + bval);
        if (which == 2)
          vto[((size_t)((b * 16 + h) * 64 + d)) * 2048 + s] = o;
        else if (which == 0)
          qo[((size_t)((b * 16 + h) * 2048 + s)) * 64 + d] = o;
        else
          ko[((size_t)((b * 16 + h) * 2048 + s)) * 64 + d] = o;
      }
    }
  }
}

// ---------------- RoPE (interleaved pairs) on q,k in place ----------------
// layout (bh, s, d); pair index = bh*2048*32 + s*32 + dp  -> one uint per pair.
__global__ void rope_kernel(unsigned int* __restrict__ q, unsigned int* __restrict__ k,
                            const float* __restrict__ cp, const float* __restrict__ sp) {
  const int idx = blockIdx.x * blockDim.x + threadIdx.x;
  if (idx >= (1 << 22)) return;              // 2 tensors * 2^21 pairs
  unsigned int* base = (idx >> 21) ? k : q;
  const int pid = idx & ((1 << 21) - 1);
  const int dp = pid & 31;
  const int s  = (pid >> 5) & 2047;
  const float c  = cp[s * 32 + dp];
  const float sn = sp[s * 32 + dp];
  const unsigned int pv = base[pid];
  const float a = b2f((unsigned short)(pv & 0xffff));
  const float b = b2f((unsigned short)(pv >> 16));
  const float orr = a * c - b * sn;
  const float oii = a * sn + b * c;
  base[pid] = (unsigned int)f2b(orr) | ((unsigned int)f2b(oii) << 16);
}

// ---------------- flash attention ----------------
// grid (bh=32, qblock=16); block 256 thr = 4 waves; wave w owns q-rows w*32..w*32+31.
__global__ __launch_bounds__(256) void flash_kernel(
    const unsigned short* __restrict__ Q,    // [32][2048][64]
    const unsigned short* __restrict__ K,    // [32][2048][64]
    const unsigned short* __restrict__ VT,   // [32][64][2048]
    unsigned short* __restrict__ O)          // [2][2048][1024]
{
  constexpr int AS = 72;                     // padded stride (64+8) bf16
  __shared__ unsigned short Qs[128 * AS];
  __shared__ unsigned short Ks[64 * AS];
  __shared__ unsigned short Vs[64 * AS];     // V^T tile: [d][t]
  __shared__ unsigned short Ps[128 * AS];
  const int tid = threadIdx.x;
  const int w = tid >> 6, l = tid & 63, lm = l & 15, quad = l >> 4;
  const int bh = blockIdx.x, qb = blockIdx.y;

  const size_t qbase = ((size_t)bh * 2048 + (size_t)qb * 128) * 64;
  for (int c = tid; c < 1024; c += 256) {    // 128 rows x 8 chunks of 16B
    const int row = c >> 3, g = c & 7;
    *(uint4*)(Qs + row * AS + g * 8) = *(const uint4*)(Q + qbase + row * 64 + g * 8);
  }

  const f32x4 fzero = {0.f, 0.f, 0.f, 0.f};
  f32x4 Oacc[2][4];
#pragma unroll
  for (int i = 0; i < 2; ++i)
#pragma unroll
    for (int jo = 0; jo < 4; ++jo) Oacc[i][jo] = fzero;
  float mrow[2][4], lrow[2][4];
#pragma unroll
  for (int i = 0; i < 2; ++i)
#pragma unroll
    for (int r = 0; r < 4; ++r) { mrow[i][r] = -1e30f; lrow[i][r] = 0.f; }

  const int nkv = 2 * qb + 2;                // causal: only tiles with any t <= m
  for (int kt = 0; kt < nkv; ++kt) {
    __syncthreads();                         // prev iter done reading Ks/Vs
    const size_t kbase = ((size_t)bh * 2048 + (size_t)kt * 64) * 64;
    const size_t vbase = (size_t)bh * 64 * 2048 + (size_t)kt * 64;
    for (int c = tid; c < 512; c += 256) {   // 64 rows x 8 chunks
      const int row = c >> 3, g = c & 7;
      *(uint4*)(Ks + row * AS + g * 8) = *(const uint4*)(K + kbase + row * 64 + g * 8);
      *(uint4*)(Vs + row * AS + g * 8) = *(const uint4*)(VT + vbase + (size_t)row * 2048 + g * 8);
    }
    __syncthreads();

    // S = Q K^T (scale applied after)
    f32x4 Sc[2][4];
#pragma unroll
    for (int i = 0; i < 2; ++i)
#pragma unroll
      for (int j = 0; j < 4; ++j) Sc[i][j] = fzero;
#pragma unroll
    for (int kc = 0; kc < 2; ++kc) {
      bf16x8 aq[2], bk[4];
#pragma unroll
      for (int i = 0; i < 2; ++i)
        aq[i] = *(const bf16x8*)(Qs + (w * 32 + i * 16 + lm) * AS + kc * 32 + quad * 8);
#pragma unroll
      for (int j = 0; j < 4; ++j)
        bk[j] = *(const bf16x8*)(Ks + (j * 16 + lm) * AS + kc * 32 + quad * 8);
#pragma unroll
      for (int i = 0; i < 2; ++i)
#pragma unroll
        for (int j = 0; j < 4; ++j)
          Sc[i][j] = __builtin_amdgcn_mfma_f32_16x16x32_bf16(aq[i], bk[j], Sc[i][j], 0, 0, 0);
    }

    // online softmax; write P (bf16) into wave-private LDS rows
#pragma unroll
    for (int i = 0; i < 2; ++i) {
#pragma unroll
      for (int r = 0; r < 4; ++r) {
        const int mg = qb * 128 + w * 32 + i * 16 + quad * 4 + r;
        float sv[4];
        float mx = -1e30f;
#pragma unroll
        for (int j = 0; j < 4; ++j) {
          float s = Sc[i][j][r] * 0.125f;    // 1/sqrt(64)
          const int tg = kt * 64 + j * 16 + lm;
          if (tg > mg) s = -1e30f;           // causal mask
          sv[j] = s;
          mx = fmaxf(mx, s);
        }
#pragma unroll
        for (int off = 1; off < 16; off <<= 1) mx = fmaxf(mx, __shfl_xor(mx, off, 64));
        const float mnew  = fmaxf(mrow[i][r], mx);
        const float alpha = __expf(mrow[i][r] - mnew);
        mrow[i][r] = mnew;
        float ps = 0.f;
#pragma unroll
        for (int j = 0; j < 4; ++j) {
          const float p = __expf(sv[j] - mnew);
          ps += p;
          Ps[(w * 32 + i * 16 + quad * 4 + r) * AS + j * 16 + lm] = f2b(p);
        }
#pragma unroll
        for (int off = 1; off < 16; off <<= 1) ps += __shfl_xor(ps, off, 64);
        lrow[i][r] = lrow[i][r] * alpha + ps;
#pragma unroll
        for (int jo = 0; jo < 4; ++jo) Oacc[i][jo][r] *= alpha;
      }
    }

    // O += P V   (P rows are wave-private; Vs is [d][t] so B-frag reads contiguous)
#pragma unroll
    for (int kc = 0; kc < 2; ++kc) {
      bf16x8 ap[2], bv[4];
#pragma unroll
      for (int i = 0; i < 2; ++i)
        ap[i] = *(const bf16x8*)(Ps + (w * 32 + i * 16 + lm) * AS + kc * 32 + quad * 8);
#pragma unroll
      for (int jo = 0; jo < 4; ++jo)
        bv[jo] = *(const bf16x8*)(Vs + (jo * 16 + lm) * AS + kc * 32 + quad * 8);
#pragma unroll
      for (int i = 0; i < 2; ++i)
#pragma unroll
        for (int jo = 0; jo < 4; ++jo)
          Oacc[i][jo] = __builtin_amdgcn_mfma_f32_16x16x32_bf16(ap[i], bv[jo], Oacc[i][jo], 0, 0, 0);
    }
  }

  // epilogue: normalize, write o_bf (b, s, h*64+d)
  const int b = bh >> 4, h = bh & 15;
#pragma unroll
  for (int i = 0; i < 2; ++i)
#pragma unroll
    for (int jo = 0; jo < 4; ++jo)
#pragma unroll
      for (int r = 0; r < 4; ++r) {
        const int s   = qb * 128 + w * 32 + i * 16 + quad * 4 + r;
        const int col = h * 64 + jo * 16 + lm;
        O[((size_t)b * 2048 + s) * 1024 + col] = f2b(Oacc[i][jo][r] / lrow[i][r]);
      }
}

// ---------------- output projection GEMM ----------------
// out[4096,1024] = Obf[4096,1024] @ Wo[1024,1024]^T + bias  (fp32 out)
__global__ __launch_bounds__(256) void oproj_gemm_kernel(
    const unsigned short* __restrict__ A,    // o_bf [4096][1024]
    const unsigned short* __restrict__ W,    // wo_bf [1024][1024]
    const float* __restrict__ bias,
    float* __restrict__ out)
{
  __shared__ unsigned short As[128 * 32];
  __shared__ unsigned short Bs[128 * 32];
  const int tid = threadIdx.x;
  const int w = tid >> 6, l = tid & 63;
  const int lm = l & 15, quad = l >> 4;
  const int m0 = blockIdx.y * 128;
  const int n0 = blockIdx.x * 128;
  const int wm = (w >> 1) * 64, wn = (w & 1) * 64;

  const f32x4 fzero = {0.f, 0.f, 0.f, 0.f};
  f32x4 acc[4][4];
#pragma unroll
  for (int i = 0; i < 4; ++i)
#pragma unroll
    for (int j = 0; j < 4; ++j) acc[i][j] = fzero;

  const int rowS = w * 16 + lm;
  for (int k0 = 0; k0 < 1024; k0 += 32) {
    uint4 ra[2], rb[2];
#pragma unroll
    for (int p = 0; p < 2; ++p) {
      const int row = rowS + p * 64;
      ra[p] = *(const uint4*)(A + (size_t)(m0 + row) * 1024 + k0 + quad * 8);
      rb[p] = *(const uint4*)(W + (size_t)(n0 + row) * 1024 + k0 + quad * 8);
    }
    __syncthreads();
#pragma unroll
    for (int p = 0; p < 2; ++p) {
      *(uint4*)(As + (size_t)(w * 64 + l + p * 256) * 8) = ra[p];
      *(uint4*)(Bs + (size_t)(w * 64 + l + p * 256) * 8) = rb[p];
    }
    __syncthreads();
    bf16x8 af[4], bfc[4];
#pragma unroll
    for (int i = 0; i < 4; ++i)
      af[i] = *(const bf16x8*)(As + (size_t)((((w >> 1) * 4 + i) * 64 + l)) * 8);
#pragma unroll
    for (int j = 0; j < 4; ++j)
      bfc[j] = *(const bf16x8*)(Bs + (size_t)((((w & 1) * 4 + j) * 64 + l)) * 8);
#pragma unroll
    for (int i = 0; i < 4; ++i)
#pragma unroll
      for (int j = 0; j < 4; ++j)
        acc[i][j] = __builtin_amdgcn_mfma_f32_16x16x32_bf16(af[i], bfc[j], acc[i][j], 0, 0, 0);
  }

#pragma unroll
  for (int i = 0; i < 4; ++i) {
#pragma unroll
    for (int j = 0; j < 4; ++j) {
      const int n = n0 + wn + j * 16 + lm;
      const float bval = bias[n];
#pragma unroll
      for (int r = 0; r < 4; ++r) {
        const int m = m0 + wm + i * 16 + quad * 4 + r;
        out[(size_t)m * 1024 + n] = acc[i][j][r] + bval;
      }
    }
  }
}

// ---------------- host launch ----------------
extern "C" void kernel_launch(void* const* d_in, const int* in_sizes, int n_in,
                              void* d_out, int out_size, void* d_ws, size_t ws_size,
                              hipStream_t stream) {
  (void)in_sizes; (void)n_in; (void)out_size; (void)ws_size;
  const float* x  = (const float*)d_in[0];
  const float* cp = (const float*)d_in[1];
  const float* sp = (const float*)d_in[2];
  const float* wq = (const float*)d_in[3];
  const float* bq = (const float*)d_in[4];
  const float* wk = (const float*)d_in[5];
  const float* bk = (const float*)d_in[6];
  const float* wv = (const float*)d_in[7];
  const float* bv = (const float*)d_in[8];
  const float* wo = (const float*)d_in[9];
  const float* bo = (const float*)d_in[10];
  float* out = (float*)d_out;

  // workspace layout (ushorts): 48 MB total
  unsigned short* xbf  = (unsigned short*)d_ws;          // 4M
  unsigned short* wqkv = xbf  + (size_t)4 * 1024 * 1024; // 3M (wq|wk|wv stacked)
  unsigned short* wobf = wqkv + (size_t)3 * 1024 * 1024; // 1M
  unsigned short* qbf  = wobf + (size_t)1 * 1024 * 1024; // 4M (bh,s,d)
  unsigned short* kbf  = qbf  + (size_t)4 * 1024 * 1024; // 4M (bh,s,d)
  unsigned short* vtbf = kbf  + (size_t)4 * 1024 * 1024; // 4M (bh,d,s)
  unsigned short* obf  = vtbf + (size_t)4 * 1024 * 1024; // 4M (b,s,h*64+d)

  hipLaunchKernelGGL(cast_kernel, dim3(4096), dim3(256), 0, stream, x, xbf, 1048576);
  hipLaunchKernelGGL(cast_kernel, dim3(1024), dim3(256), 0, stream, wq, wqkv, 262144);
  hipLaunchKernelGGL(cast_kernel, dim3(1024), dim3(256), 0, stream, wk, wqkv + 1048576, 262144);
  hipLaunchKernelGGL(cast_kernel, dim3(1024), dim3(256), 0, stream, wv, wqkv + 2097152, 262144);
  hipLaunchKernelGGL(cast_kernel, dim3(1024), dim3(256), 0, stream, wo, wobf, 262144);

  hipLaunchKernelGGL(qkv_gemm_kernel, dim3(24, 32), dim3(256), 0, stream,
                     xbf, wqkv, bq, bk, bv, qbf, kbf, vtbf);
  hipLaunchKernelGGL(rope_kernel, dim3(16384), dim3(256), 0, stream,
                     (unsigned int*)qbf, (unsigned int*)kbf, cp, sp);
  hipLaunchKernelGGL(flash_kernel, dim3(32, 16), dim3(256), 0, stream,
                     qbf, kbf, vtbf, obf);
  hipLaunchKernelGGL(oproj_gemm_kernel, dim3(8, 32), dim3(256), 0, stream,
                     obf, wobf, bo, out);
}

// Round 2
// 303.100 us; speedup vs baseline: 1.4545x; 1.4545x over previous
//
#include <hip/hip_runtime.h>
#include <stdint.h>
#include <stddef.h>

// ============================================================================
// MHA block on gfx950, bf16 MFMA pipeline.  B=2,S=2048,D=1024,H=16,hd=64.
// R2 changes vs R1 (latency-bound diagnosis, MfmaUtil 5.7%):
//  - GEMMs stage via __builtin_amdgcn_global_load_lds width=16 (m97 pattern).
//  - V written row-major (bh,s,d); flash transposes V tile in LDS on stage.
//  - RoPE fused into qkv epilogue (shfl_xor pair exchange); rope kernel gone.
//  - Flash: Q frags in registers, interior tiles skip causal mask, heavy qb first.
// MFMA layouts (verified m89/m91/m120):
//   A-frag: A[m=lane&15][k=(lane>>4)*8+j]  (16B/lane contiguous)
//   B-frag: B[k=(lane>>4)*8+j][n=lane&15] == row-major read of B^T tile
//   C/D:    col=lane&15, row=(lane>>4)*4+reg
// GEMM LDS fragment-major: chunk(row,kc) = (row>>4)*64 + kc*16 + (row&15);
// wave-w stage base chunk = w*64 + p*256, lane l at +l  -> exactly the
// wave-uniform-base + lane*16B order global_load_lds requires.
// ============================================================================

typedef __bf16 bf16x8 __attribute__((ext_vector_type(8)));
typedef float  f32x4  __attribute__((ext_vector_type(4)));

__device__ __forceinline__ unsigned short f2b(float f) {
  union { float f; uint32_t u; } v; v.f = f;
  uint32_t u = v.u;
  return (unsigned short)((u + 0x7FFFu + ((u >> 16) & 1u)) >> 16);  // RNE
}

__device__ __forceinline__ void async16(const void* g, void* l) {
  __builtin_amdgcn_global_load_lds(
      (const __attribute__((address_space(1))) void*)g,
      (__attribute__((address_space(3))) void*)l, 16, 0, 0);
}

// ---------------- cast x f32 -> bf16 ----------------
__global__ void cast_kernel(const float* __restrict__ in,
                            unsigned short* __restrict__ out, int n4) {
  int i = blockIdx.x * blockDim.x + threadIdx.x;
  if (i >= n4) return;
  float4 v = ((const float4*)in)[i];
  ushort4 o;
  o.x = f2b(v.x); o.y = f2b(v.y); o.z = f2b(v.z); o.w = f2b(v.w);
  ((ushort4*)out)[i] = o;
}

// ---------------- cast all 4 weight matrices in one launch ----------------
// wq|wk|wv -> stacked wqkv[3M], wo -> wobf[1M].  Each is 2^18 float4 chunks.
__global__ void cast_w_kernel(const float* __restrict__ wq, const float* __restrict__ wk,
                              const float* __restrict__ wv, const float* __restrict__ wo,
                              unsigned short* __restrict__ wqkv,
                              unsigned short* __restrict__ wobf) {
  int i = blockIdx.x * blockDim.x + threadIdx.x;   // 0 .. 4*2^18-1
  const int sel = i >> 18, k = i & ((1 << 18) - 1);
  const float* src = (sel == 0) ? wq : (sel == 1) ? wk : (sel == 2) ? wv : wo;
  float4 v = ((const float4*)src)[k];
  ushort4 o;
  o.x = f2b(v.x); o.y = f2b(v.y); o.z = f2b(v.z); o.w = f2b(v.w);
  if (sel < 3) ((ushort4*)wqkv)[(size_t)sel * 262144 + k] = o;
  else         ((ushort4*)wobf)[k] = o;
}

// ---------------- fused QKV projection GEMM (+bias, +RoPE on q/k) ----------
// C[4096,3072] = Xbf[4096,1024] @ Wqkv[3072,1024]^T, 128x128x32 tiles.
__global__ __launch_bounds__(256) void qkv_gemm_kernel(
    const unsigned short* __restrict__ A,    // x_bf [4096][1024]
    const unsigned short* __restrict__ W,    // wqkv [3072][1024]
    const float* __restrict__ biasq, const float* __restrict__ biask,
    const float* __restrict__ biasv,
    const float* __restrict__ cp, const float* __restrict__ sp,  // [2048][32]
    unsigned short* __restrict__ qo,         // [32][2048][64]
    unsigned short* __restrict__ ko,         // [32][2048][64]
    unsigned short* __restrict__ vo)         // [32][2048][64]
{
  __shared__ unsigned short As[128 * 32];
  __shared__ unsigned short Bs[128 * 32];
  const int tid  = threadIdx.x;
  const int w    = tid >> 6, l = tid & 63;
  const int lm   = l & 15,  quad = l >> 4;
  const int nblk = blockIdx.x;               // 0..23
  const int m0   = blockIdx.y * 128;
  const int n0g  = nblk * 128;               // row into stacked [3072] weights
  const int wm   = (w >> 1) * 64, wn = (w & 1) * 64;

  const f32x4 fzero = {0.f, 0.f, 0.f, 0.f};
  f32x4 acc[4][4];
#pragma unroll
  for (int i = 0; i < 4; ++i)
#pragma unroll
    for (int j = 0; j < 4; ++j) acc[i][j] = fzero;

  const int rowS = w * 16 + lm;              // staging row (+p*64), kchunk = quad
  for (int k0 = 0; k0 < 1024; k0 += 32) {
    __syncthreads();                         // LDS free (prev iter's ds_reads done)
#pragma unroll
    for (int p = 0; p < 2; ++p) {
      const int row = rowS + p * 64;
      async16(A + (size_t)(m0 + row) * 1024 + k0 + quad * 8,
              As + (size_t)(w * 64 + p * 256) * 8);
      async16(W + (size_t)(n0g + row) * 1024 + k0 + quad * 8,
              Bs + (size_t)(w * 64 + p * 256) * 8);
    }
    __syncthreads();                         // drains vmcnt -> tile in LDS
    bf16x8 af[4], bfc[4];
#pragma unroll
    for (int i = 0; i < 4; ++i)
      af[i] = *(const bf16x8*)(As + (size_t)((((w >> 1) * 4 + i) * 64 + l)) * 8);
#pragma unroll
    for (int j = 0; j < 4; ++j)
      bfc[j] = *(const bf16x8*)(Bs + (size_t)((((w & 1) * 4 + j) * 64 + l)) * 8);
#pragma unroll
    for (int i = 0; i < 4; ++i)
#pragma unroll
      for (int j = 0; j < 4; ++j)
        acc[i][j] = __builtin_amdgcn_mfma_f32_16x16x32_bf16(af[i], bfc[j], acc[i][j], 0, 0, 0);
  }

  const int which = nblk >> 3;               // 0=q 1=k 2=v
  const int n0    = (nblk & 7) * 128;        // col within 1024
  const float* bias = (which == 0) ? biasq : (which == 1) ? biask : biasv;
  unsigned short* dst = (which == 0) ? qo : (which == 1) ? ko : vo;
#pragma unroll
  for (int i = 0; i < 4; ++i) {
#pragma unroll
    for (int j = 0; j < 4; ++j) {
      const int n = n0 + wn + j * 16 + lm;
      const float bval = bias[n];
      const int h = n >> 6, d = n & 63;
#pragma unroll
      for (int r = 0; r < 4; ++r) {
        const int m = m0 + wm + i * 16 + quad * 4 + r;
        const int b = m >> 11, srow = m & 2047;
        float val = acc[i][j][r] + bval;
        if (which != 2) {
          // RoPE: pair partner is lane^1 (adjacent n), a=even-d val, b=odd-d val
          const float c  = cp[srow * 32 + (d >> 1)];
          const float sn = sp[srow * 32 + (d >> 1)];
          const float part = __shfl_xor(val, 1, 64);
          val = (d & 1) ? (part * sn + val * c) : (val * c - part * sn);
        }
        dst[((size_t)((b * 16 + h) * 2048 + srow)) * 64 + d] = f2b(val);
      }
    }
  }
}

// ---------------- flash attention ----------------
// grid (bh=32, 16); block 256 thr = 4 waves; wave w owns q-rows w*32..w*32+31.
// Heavy q-blocks dispatch first (qb = 15 - blockIdx.y).
__global__ __launch_bounds__(256) void flash_kernel(
    const unsigned short* __restrict__ Q,    // [32][2048][64]
    const unsigned short* __restrict__ K,    // [32][2048][64]
    const unsigned short* __restrict__ V,    // [32][2048][64]
    unsigned short* __restrict__ O)          // [2][2048][1024]
{
  constexpr int AS = 72;                     // padded stride (64+8) bf16
  __shared__ unsigned short Ks[64 * AS];
  __shared__ unsigned short Vs[64 * AS];     // transposed tile: [d][t]
  __shared__ unsigned short Ps[128 * AS];
  const int tid = threadIdx.x;
  const int w = tid >> 6, l = tid & 63, lm = l & 15, quad = l >> 4;
  const int bh = blockIdx.x, qb = 15 - blockIdx.y;

  // Q fragments straight to registers (rows are wave-private)
  const size_t qbase = ((size_t)bh * 2048 + (size_t)qb * 128) * 64;
  bf16x8 aq[2][2];                            // [kc][i]
#pragma unroll
  for (int kc = 0; kc < 2; ++kc)
#pragma unroll
    for (int i = 0; i < 2; ++i)
      aq[kc][i] = *(const bf16x8*)(Q + qbase + (size_t)(w * 32 + i * 16 + lm) * 64 + kc * 32 + quad * 8);

  const f32x4 fzero = {0.f, 0.f, 0.f, 0.f};
  f32x4 Oacc[2][4];
#pragma unroll
  for (int i = 0; i < 2; ++i)
#pragma unroll
    for (int jo = 0; jo < 4; ++jo) Oacc[i][jo] = fzero;
  float mrow[2][4], lrow[2][4];
#pragma unroll
  for (int i = 0; i < 2; ++i)
#pragma unroll
    for (int r = 0; r < 4; ++r) { mrow[i][r] = -1e30f; lrow[i][r] = 0.f; }

  // V-transpose staging coords: 4 threads/row, 16 cols each
  const int vrow = tid >> 2, vcg = tid & 3;

  const int nkv = 2 * qb + 2;
  for (int kt = 0; kt < nkv; ++kt) {
    __syncthreads();                         // prev iter done reading Ks/Vs
    const size_t kbase = ((size_t)bh * 2048 + (size_t)kt * 64) * 64;
    for (int c = tid; c < 512; c += 256) {   // K: 64 rows x 8 chunks of 16B
      const int row = c >> 3, g = c & 7;
      *(uint4*)(Ks + row * AS + g * 8) = *(const uint4*)(K + kbase + row * 64 + g * 8);
    }
    {                                        // V: load row-major, store transposed
      uint4 v0 = *(const uint4*)(V + kbase + (size_t)vrow * 64 + vcg * 16);
      uint4 v1 = *(const uint4*)(V + kbase + (size_t)vrow * 64 + vcg * 16 + 8);
      const unsigned short* p0 = (const unsigned short*)&v0;
      const unsigned short* p1 = (const unsigned short*)&v1;
#pragma unroll
      for (int j = 0; j < 8; ++j) {
        Vs[(vcg * 16 + j) * AS + vrow]     = p0[j];
        Vs[(vcg * 16 + 8 + j) * AS + vrow] = p1[j];
      }
    }
    __syncthreads();

    // S = Q K^T
    f32x4 Sc[2][4];
#pragma unroll
    for (int i = 0; i < 2; ++i)
#pragma unroll
      for (int j = 0; j < 4; ++j) Sc[i][j] = fzero;
#pragma unroll
    for (int kc = 0; kc < 2; ++kc) {
      bf16x8 bk[4];
#pragma unroll
      for (int j = 0; j < 4; ++j)
        bk[j] = *(const bf16x8*)(Ks + (j * 16 + lm) * AS + kc * 32 + quad * 8);
#pragma unroll
      for (int i = 0; i < 2; ++i)
#pragma unroll
        for (int j = 0; j < 4; ++j)
          Sc[i][j] = __builtin_amdgcn_mfma_f32_16x16x32_bf16(aq[kc][i], bk[j], Sc[i][j], 0, 0, 0);
    }

    // online softmax (mask only needed on the two diagonal tiles)
    const bool diag = (kt >= 2 * qb);
#pragma unroll
    for (int i = 0; i < 2; ++i) {
#pragma unroll
      for (int r = 0; r < 4; ++r) {
        const int mg = qb * 128 + w * 32 + i * 16 + quad * 4 + r;
        float sv[4];
        float mx = -1e30f;
#pragma unroll
        for (int j = 0; j < 4; ++j) {
          float s = Sc[i][j][r] * 0.125f;    // 1/sqrt(64)
          if (diag) {
            const int tg = kt * 64 + j * 16 + lm;
            if (tg > mg) s = -1e30f;
          }
          sv[j] = s;
          mx = fmaxf(mx, s);
        }
#pragma unroll
        for (int off = 1; off < 16; off <<= 1) mx = fmaxf(mx, __shfl_xor(mx, off, 64));
        const float mnew  = fmaxf(mrow[i][r], mx);
        const float alpha = __expf(mrow[i][r] - mnew);
        mrow[i][r] = mnew;
        float ps = 0.f;
#pragma unroll
        for (int j = 0; j < 4; ++j) {
          const float p = __expf(sv[j] - mnew);
          ps += p;
          Ps[(w * 32 + i * 16 + quad * 4 + r) * AS + j * 16 + lm] = f2b(p);
        }
#pragma unroll
        for (int off = 1; off < 16; off <<= 1) ps += __shfl_xor(ps, off, 64);
        lrow[i][r] = lrow[i][r] * alpha + ps;
#pragma unroll
        for (int jo = 0; jo < 4; ++jo) Oacc[i][jo][r] *= alpha;
      }
    }

    // O += P V  (P rows wave-private; Vs is [d][t] so B-frags read contiguous)
#pragma unroll
    for (int kc = 0; kc < 2; ++kc) {
      bf16x8 ap[2], bv[4];
#pragma unroll
      for (int i = 0; i < 2; ++i)
        ap[i] = *(const bf16x8*)(Ps + (w * 32 + i * 16 + lm) * AS + kc * 32 + quad * 8);
#pragma unroll
      for (int jo = 0; jo < 4; ++jo)
        bv[jo] = *(const bf16x8*)(Vs + (jo * 16 + lm) * AS + kc * 32 + quad * 8);
#pragma unroll
      for (int i = 0; i < 2; ++i)
#pragma unroll
        for (int jo = 0; jo < 4; ++jo)
          Oacc[i][jo] = __builtin_amdgcn_mfma_f32_16x16x32_bf16(ap[i], bv[jo], Oacc[i][jo], 0, 0, 0);
    }
  }

  // epilogue: normalize, write o_bf (b, s, h*64+d)
  const int b = bh >> 4, h = bh & 15;
#pragma unroll
  for (int i = 0; i < 2; ++i)
#pragma unroll
    for (int jo = 0; jo < 4; ++jo)
#pragma unroll
      for (int r = 0; r < 4; ++r) {
        const int s   = qb * 128 + w * 32 + i * 16 + quad * 4 + r;
        const int col = h * 64 + jo * 16 + lm;
        O[((size_t)b * 2048 + s) * 1024 + col] = f2b(Oacc[i][jo][r] / lrow[i][r]);
      }
}

// ---------------- output projection GEMM ----------------
// out[4096,1024] = Obf[4096,1024] @ Wo[1024,1024]^T + bias  (fp32 out)
__global__ __launch_bounds__(256) void oproj_gemm_kernel(
    const unsigned short* __restrict__ A,    // o_bf [4096][1024]
    const unsigned short* __restrict__ W,    // wo_bf [1024][1024]
    const float* __restrict__ bias,
    float* __restrict__ out)
{
  __shared__ unsigned short As[128 * 32];
  __shared__ unsigned short Bs[128 * 32];
  const int tid = threadIdx.x;
  const int w = tid >> 6, l = tid & 63;
  const int lm = l & 15, quad = l >> 4;
  const int m0 = blockIdx.y * 128;
  const int n0 = blockIdx.x * 128;
  const int wm = (w >> 1) * 64, wn = (w & 1) * 64;

  const f32x4 fzero = {0.f, 0.f, 0.f, 0.f};
  f32x4 acc[4][4];
#pragma unroll
  for (int i = 0; i < 4; ++i)
#pragma unroll
    for (int j = 0; j < 4; ++j) acc[i][j] = fzero;

  const int rowS = w * 16 + lm;
  for (int k0 = 0; k0 < 1024; k0 += 32) {
    __syncthreads();
#pragma unroll
    for (int p = 0; p < 2; ++p) {
      const int row = rowS + p * 64;
      async16(A + (size_t)(m0 + row) * 1024 + k0 + quad * 8,
              As + (size_t)(w * 64 + p * 256) * 8);
      async16(W + (size_t)(n0 + row) * 1024 + k0 + quad * 8,
              Bs + (size_t)(w * 64 + p * 256) * 8);
    }
    __syncthreads();
    bf16x8 af[4], bfc[4];
#pragma unroll
    for (int i = 0; i < 4; ++i)
      af[i] = *(const bf16x8*)(As + (size_t)((((w >> 1) * 4 + i) * 64 + l)) * 8);
#pragma unroll
    for (int j = 0; j < 4; ++j)
      bfc[j] = *(const bf16x8*)(Bs + (size_t)((((w & 1) * 4 + j) * 64 + l)) * 8);
#pragma unroll
    for (int i = 0; i < 4; ++i)
#pragma unroll
      for (int j = 0; j < 4; ++j)
        acc[i][j] = __builtin_amdgcn_mfma_f32_16x16x32_bf16(af[i], bfc[j], acc[i][j], 0, 0, 0);
  }

#pragma unroll
  for (int i = 0; i < 4; ++i) {
#pragma unroll
    for (int j = 0; j < 4; ++j) {
      const int n = n0 + wn + j * 16 + lm;
      const float bval = bias[n];
#pragma unroll
      for (int r = 0; r < 4; ++r) {
        const int m = m0 + wm + i * 16 + quad * 4 + r;
        out[(size_t)m * 1024 + n] = acc[i][j][r] + bval;
      }
    }
  }
}

// ---------------- host launch ----------------
extern "C" void kernel_launch(void* const* d_in, const int* in_sizes, int n_in,
                              void* d_out, int out_size, void* d_ws, size_t ws_size,
                              hipStream_t stream) {
  (void)in_sizes; (void)n_in; (void)out_size; (void)ws_size;
  const float* x  = (const float*)d_in[0];
  const float* cp = (const float*)d_in[1];
  const float* sp = (const float*)d_in[2];
  const float* wq = (const float*)d_in[3];
  const float* bq = (const float*)d_in[4];
  const float* wk = (const float*)d_in[5];
  const float* bk = (const float*)d_in[6];
  const float* wv = (const float*)d_in[7];
  const float* bv = (const float*)d_in[8];
  const float* wo = (const float*)d_in[9];
  const float* bo = (const float*)d_in[10];
  float* out = (float*)d_out;

  // workspace layout (ushorts): 48 MB total
  unsigned short* xbf  = (unsigned short*)d_ws;          // 4M
  unsigned short* wqkv = xbf  + (size_t)4 * 1024 * 1024; // 3M (wq|wk|wv stacked)
  unsigned short* wobf = wqkv + (size_t)3 * 1024 * 1024; // 1M
  unsigned short* qbf  = wobf + (size_t)1 * 1024 * 1024; // 4M (bh,s,d)
  unsigned short* kbf  = qbf  + (size_t)4 * 1024 * 1024; // 4M (bh,s,d)
  unsigned short* vbf  = kbf  + (size_t)4 * 1024 * 1024; // 4M (bh,s,d)
  unsigned short* obf  = vbf  + (size_t)4 * 1024 * 1024; // 4M (b,s,h*64+d)

  hipLaunchKernelGGL(cast_kernel, dim3(4096), dim3(256), 0, stream, x, xbf, 1048576);
  hipLaunchKernelGGL(cast_w_kernel, dim3(4096), dim3(256), 0, stream,
                     wq, wk, wv, wo, wqkv, wobf);

  hipLaunchKernelGGL(qkv_gemm_kernel, dim3(24, 32), dim3(256), 0, stream,
                     xbf, wqkv, bq, bk, bv, cp, sp, qbf, kbf, vbf);
  hipLaunchKernelGGL(flash_kernel, dim3(32, 16), dim3(256), 0, stream,
                     qbf, kbf, vbf, obf);
  hipLaunchKernelGGL(oproj_gemm_kernel, dim3(8, 32), dim3(256), 0, stream,
                     obf, wobf, bo, out);
}

// Round 4
// 240.366 us; speedup vs baseline: 1.8341x; 1.2610x over previous
//
#include <hip/hip_runtime.h>
#include <stdint.h>
#include <stddef.h>

// ============================================================================
// MHA block on gfx950, bf16 MFMA pipeline.  B=2,S=2048,D=1024,H=16,hd=64.
// R4 = R3 + one-line causal-mask fix (needmask off-by-one let <=15 future
// keys leak on waves whose 16-row band starts mid-tile).
// R3 changes vs R2 (flash: MfmaUtil 5.7%, 6.1M LDS conflicts, occ 12.5%):
//  - flash computes S^T = K*Q^T (swap MFMA ports): t in-lane -> softmax
//    reductions mostly in-register (2 shuffles), P written as packed b64.
//  - K and V^T stored in tiled fragment-major global layout by qkv_gemm:
//    flash stages each 64x64 tile with one global_load_lds(16B)/thread.
//  - flash blocks: 512 threads (8 waves x 16 q-rows).
// MFMA layouts (verified m89/m91/m120):
//   A-frag: A[m=lane&15][k=(lane>>4)*8+j]  (16B/lane contiguous)
//   B-frag: B[k=(lane>>4)*8+j][n=lane&15] == row-major read of B^T tile
//   C/D:    col=lane&15, row=(lane>>4)*4+reg
// ============================================================================

typedef __bf16 bf16x8 __attribute__((ext_vector_type(8)));
typedef float  f32x4  __attribute__((ext_vector_type(4)));

__device__ __forceinline__ unsigned short f2b(float f) {
  union { float f; uint32_t u; } v; v.f = f;
  uint32_t u = v.u;
  return (unsigned short)((u + 0x7FFFu + ((u >> 16) & 1u)) >> 16);  // RNE
}

__device__ __forceinline__ void async16(const void* g, void* l) {
  __builtin_amdgcn_global_load_lds(
      (const __attribute__((address_space(1))) void*)g,
      (__attribute__((address_space(3))) void*)l, 16, 0, 0);
}

// ---------------- cast x f32 -> bf16 ----------------
__global__ void cast_kernel(const float* __restrict__ in,
                            unsigned short* __restrict__ out, int n4) {
  int i = blockIdx.x * blockDim.x + threadIdx.x;
  if (i >= n4) return;
  float4 v = ((const float4*)in)[i];
  ushort4 o;
  o.x = f2b(v.x); o.y = f2b(v.y); o.z = f2b(v.z); o.w = f2b(v.w);
  ((ushort4*)out)[i] = o;
}

// ---------------- cast all 4 weight matrices in one launch ----------------
__global__ void cast_w_kernel(const float* __restrict__ wq, const float* __restrict__ wk,
                              const float* __restrict__ wv, const float* __restrict__ wo,
                              unsigned short* __restrict__ wqkv,
                              unsigned short* __restrict__ wobf) {
  int i = blockIdx.x * blockDim.x + threadIdx.x;   // 0 .. 4*2^18-1
  const int sel = i >> 18, k = i & ((1 << 18) - 1);
  const float* src = (sel == 0) ? wq : (sel == 1) ? wk : (sel == 2) ? wv : wo;
  float4 v = ((const float4*)src)[k];
  ushort4 o;
  o.x = f2b(v.x); o.y = f2b(v.y); o.z = f2b(v.z); o.w = f2b(v.w);
  if (sel < 3) ((ushort4*)wqkv)[(size_t)sel * 262144 + k] = o;
  else         ((ushort4*)wobf)[k] = o;
}

// ---------------- fused QKV projection GEMM (+bias, +RoPE on q/k) ----------
// C[4096,3072] = Xbf[4096,1024] @ Wqkv[3072,1024]^T, 128x128x32 tiles.
// Output layouts:
//   q: [bh][2048][64] row-major (RoPE'd)
//   k: tiled frag-major: [bh][st=32][ chunk L = (d>>3)*64 + (s&63) ][8 of d]
//   v: V^T tiled frag-major: [bh][st=32][ chunk L = ((s&63)>>3)*64 + d ][8 of s]
__global__ __launch_bounds__(256) void qkv_gemm_kernel(
    const unsigned short* __restrict__ A,    // x_bf [4096][1024]
    const unsigned short* __restrict__ W,    // wqkv [3072][1024]
    const float* __restrict__ biasq, const float* __restrict__ biask,
    const float* __restrict__ biasv,
    const float* __restrict__ cp, const float* __restrict__ sp,  // [2048][32]
    unsigned short* __restrict__ qo,
    unsigned short* __restrict__ ko,
    unsigned short* __restrict__ vo)
{
  __shared__ unsigned short As[128 * 32];
  __shared__ unsigned short Bs[128 * 32];
  const int tid  = threadIdx.x;
  const int w    = tid >> 6, l = tid & 63;
  const int lm   = l & 15,  quad = l >> 4;
  const int nblk = blockIdx.x;               // 0..23
  const int m0   = blockIdx.y * 128;
  const int n0g  = nblk * 128;
  const int wm   = (w >> 1) * 64, wn = (w & 1) * 64;

  const f32x4 fzero = {0.f, 0.f, 0.f, 0.f};
  f32x4 acc[4][4];
#pragma unroll
  for (int i = 0; i < 4; ++i)
#pragma unroll
    for (int j = 0; j < 4; ++j) acc[i][j] = fzero;

  const int rowS = w * 16 + lm;
  for (int k0 = 0; k0 < 1024; k0 += 32) {
    __syncthreads();
#pragma unroll
    for (int p = 0; p < 2; ++p) {
      const int row = rowS + p * 64;
      async16(A + (size_t)(m0 + row) * 1024 + k0 + quad * 8,
              As + (size_t)(w * 64 + p * 256) * 8);
      async16(W + (size_t)(n0g + row) * 1024 + k0 + quad * 8,
              Bs + (size_t)(w * 64 + p * 256) * 8);
    }
    __syncthreads();
    bf16x8 af[4], bfc[4];
#pragma unroll
    for (int i = 0; i < 4; ++i)
      af[i] = *(const bf16x8*)(As + (size_t)((((w >> 1) * 4 + i) * 64 + l)) * 8);
#pragma unroll
    for (int j = 0; j < 4; ++j)
      bfc[j] = *(const bf16x8*)(Bs + (size_t)((((w & 1) * 4 + j) * 64 + l)) * 8);
#pragma unroll
    for (int i = 0; i < 4; ++i)
#pragma unroll
      for (int j = 0; j < 4; ++j)
        acc[i][j] = __builtin_amdgcn_mfma_f32_16x16x32_bf16(af[i], bfc[j], acc[i][j], 0, 0, 0);
  }

  const int which = nblk >> 3;               // 0=q 1=k 2=v
  const int n0    = (nblk & 7) * 128;
  const float* bias = (which == 0) ? biasq : (which == 1) ? biask : biasv;
#pragma unroll
  for (int i = 0; i < 4; ++i) {
#pragma unroll
    for (int j = 0; j < 4; ++j) {
      const int n = n0 + wn + j * 16 + lm;
      const float bval = bias[n];
      const int h = n >> 6, d = n & 63;
      float vals[4];
#pragma unroll
      for (int r = 0; r < 4; ++r) {
        const int m = m0 + wm + i * 16 + quad * 4 + r;
        const int srow = m & 2047;
        float val = acc[i][j][r] + bval;
        if (which != 2) {
          const float c  = cp[srow * 32 + (d >> 1)];
          const float sn = sp[srow * 32 + (d >> 1)];
          const float part = __shfl_xor(val, 1, 64);
          val = (d & 1) ? (part * sn + val * c) : (val * c - part * sn);
        }
        vals[r] = val;
      }
      const int mbase = m0 + wm + i * 16 + quad * 4;   // 4 consecutive s
      const int b = mbase >> 11, s0 = mbase & 2047;
      const int bh = (b << 4) + h;
      if (which == 0) {
#pragma unroll
        for (int r = 0; r < 4; ++r)
          qo[((size_t)bh * 2048 + s0 + r) * 64 + d] = f2b(vals[r]);
      } else if (which == 1) {
        // tiled: base = (bh*32 + s>>6)*4096 + ((d>>3)*64 + (s&63))*8 + (d&7)
#pragma unroll
        for (int r = 0; r < 4; ++r) {
          const int s = s0 + r;
          ko[((size_t)bh * 32 + (s >> 6)) * 4096 +
             (size_t)(((d >> 3) * 64 + (s & 63))) * 8 + (d & 7)] = f2b(vals[r]);
        }
      } else {
        // V^T tiled, 4 consecutive s -> one uint2 (8B) store
        uint32_t w0 = (uint32_t)f2b(vals[0]) | ((uint32_t)f2b(vals[1]) << 16);
        uint32_t w1 = (uint32_t)f2b(vals[2]) | ((uint32_t)f2b(vals[3]) << 16);
        uint2 pk; pk.x = w0; pk.y = w1;
        *(uint2*)(vo + ((size_t)bh * 32 + (s0 >> 6)) * 4096 +
                  (size_t)((((s0 & 63) >> 3) * 64 + d)) * 8 + (s0 & 7)) = pk;
      }
    }
  }
}

// ---------------- flash attention ----------------
// grid (bh=32, 16); block 512 thr = 8 waves; wave w owns q-rows w*16..w*16+15.
// S^T = K*Q^T formulation: t in-lane, m = lane&15.
__global__ __launch_bounds__(512, 4) void flash_kernel(
    const unsigned short* __restrict__ Q,    // [32][2048][64] row-major
    const unsigned short* __restrict__ K,    // tiled frag-major (see qkv)
    const unsigned short* __restrict__ VT,   // V^T tiled frag-major
    unsigned short* __restrict__ O)          // [2][2048][1024]
{
  constexpr int PSTRIDE = 72;                // Ps row stride (shorts)
  __shared__ unsigned short Ks[4096];        // 64x64 tile, chunk L = c*64 + t
  __shared__ unsigned short Vs[4096];        // V^T tile, chunk L = ct*64 + d
  __shared__ unsigned short Ps[128 * PSTRIDE];
  const int tid = threadIdx.x;
  const int w = tid >> 6, l = tid & 63, lm = l & 15, quad = l >> 4;
  const int bh = blockIdx.x, qb = 15 - blockIdx.y;   // heavy q-blocks first
  const int mrow_g = qb * 128 + w * 16 + lm;         // this lane's softmax row

  // Q fragment to registers: lane reads row (qb*128+w*16+lm), 8 d at quad*8
  const size_t qbase = ((size_t)bh * 2048 + (size_t)qb * 128) * 64;
  bf16x8 aq[2];
#pragma unroll
  for (int kc = 0; kc < 2; ++kc)
    aq[kc] = *(const bf16x8*)(Q + qbase + (size_t)(w * 16 + lm) * 64 + kc * 32 + quad * 8);

  const f32x4 fzero = {0.f, 0.f, 0.f, 0.f};
  f32x4 Oacc[4];
#pragma unroll
  for (int jo = 0; jo < 4; ++jo) Oacc[jo] = fzero;
  float m_i = -1e30f, l_i = 0.f;

  const int nkv = 2 * qb + 2;
  for (int kt = 0; kt < nkv; ++kt) {
    __syncthreads();                         // prev iter done reading Ks/Vs
    {
      const size_t tbase = ((size_t)bh * 32 + kt) * 4096;
      async16(K  + tbase + (size_t)tid * 8, Ks + (size_t)w * 512);
      async16(VT + tbase + (size_t)tid * 8, Vs + (size_t)w * 512);
    }
    __syncthreads();                         // tiles in LDS

    // S^T = K * Q^T : Sc[tb] holds t = tb*16+quad*4+r (rows), m = lm (col)
    f32x4 Sc[4];
#pragma unroll
    for (int tb = 0; tb < 4; ++tb) Sc[tb] = fzero;
#pragma unroll
    for (int kc = 0; kc < 2; ++kc) {
      bf16x8 ak[4];
#pragma unroll
      for (int tb = 0; tb < 4; ++tb)
        ak[tb] = *(const bf16x8*)(Ks + (size_t)(((kc * 4 + quad) * 64 + tb * 16 + lm)) * 8);
#pragma unroll
      for (int tb = 0; tb < 4; ++tb)
        Sc[tb] = __builtin_amdgcn_mfma_f32_16x16x32_bf16(ak[tb], aq[kc], Sc[tb], 0, 0, 0);
    }

    // scale + causal mask.  Mask needed iff tile's max t (kt*64+63) exceeds
    // this wave's MIN row (qb*128 + w*16).  (R3 bug: used +48 >, leaking
    // future keys when the wave band starts mid-tile.)
    const bool needmask = (kt * 64 + 63 > qb * 128 + w * 16);
    const int  mrel = mrow_g - kt * 64;      // mask t-index > mrel
    float mx = -1e30f;
#pragma unroll
    for (int tb = 0; tb < 4; ++tb) {
#pragma unroll
      for (int r = 0; r < 4; ++r) {
        float s = Sc[tb][r] * 0.125f;        // 1/sqrt(64)
        if (needmask && (tb * 16 + quad * 4 + r > mrel)) s = -1e30f;
        Sc[tb][r] = s;
        mx = fmaxf(mx, s);
      }
    }
    mx = fmaxf(mx, __shfl_xor(mx, 16, 64));
    mx = fmaxf(mx, __shfl_xor(mx, 32, 64));
    const float mnew  = fmaxf(m_i, mx);
    const float alpha = __expf(m_i - mnew);
    m_i = mnew;

    // exp, pack 4 consecutive t -> b64 write into Ps[m][t]
    float ps = 0.f;
#pragma unroll
    for (int tb = 0; tb < 4; ++tb) {
      float p0 = __expf(Sc[tb][0] - mnew), p1 = __expf(Sc[tb][1] - mnew);
      float p2 = __expf(Sc[tb][2] - mnew), p3 = __expf(Sc[tb][3] - mnew);
      ps += (p0 + p1) + (p2 + p3);
      uint2 pk;
      pk.x = (uint32_t)f2b(p0) | ((uint32_t)f2b(p1) << 16);
      pk.y = (uint32_t)f2b(p2) | ((uint32_t)f2b(p3) << 16);
      *(uint2*)(Ps + (size_t)(w * 16 + lm) * PSTRIDE + tb * 16 + quad * 4) = pk;
    }
    ps += __shfl_xor(ps, 16, 64);
    ps += __shfl_xor(ps, 32, 64);
    l_i = l_i * alpha + ps;

    // rescale Oacc: alpha lives per m=lm; O rows are quad*4+r -> shuffle
    float af4[4];
#pragma unroll
    for (int r = 0; r < 4; ++r) af4[r] = __shfl(alpha, quad * 4 + r, 64);
#pragma unroll
    for (int jo = 0; jo < 4; ++jo)
#pragma unroll
      for (int r = 0; r < 4; ++r) Oacc[jo][r] *= af4[r];

    // O += P V  (wave-private Ps rows; lgkmcnt orders write->read in-wave)
#pragma unroll
    for (int kc = 0; kc < 2; ++kc) {
      bf16x8 ap = *(const bf16x8*)(Ps + (size_t)(w * 16 + lm) * PSTRIDE + kc * 32 + quad * 8);
      bf16x8 bv[4];
#pragma unroll
      for (int jo = 0; jo < 4; ++jo)
        bv[jo] = *(const bf16x8*)(Vs + (size_t)(((kc * 4 + quad) * 64 + jo * 16 + lm)) * 8);
#pragma unroll
      for (int jo = 0; jo < 4; ++jo)
        Oacc[jo] = __builtin_amdgcn_mfma_f32_16x16x32_bf16(ap, bv[jo], Oacc[jo], 0, 0, 0);
    }
  }

  // epilogue: normalize, write o_bf (b, s, h*64+d)
  float lf[4];
#pragma unroll
  for (int r = 0; r < 4; ++r) lf[r] = 1.0f / __shfl(l_i, quad * 4 + r, 64);
  const int b = bh >> 4, h = bh & 15;
#pragma unroll
  for (int jo = 0; jo < 4; ++jo)
#pragma unroll
    for (int r = 0; r < 4; ++r) {
      const int s   = qb * 128 + w * 16 + quad * 4 + r;
      const int col = h * 64 + jo * 16 + lm;
      O[((size_t)b * 2048 + s) * 1024 + col] = f2b(Oacc[jo][r] * lf[r]);
    }
}

// ---------------- output projection GEMM ----------------
__global__ __launch_bounds__(256) void oproj_gemm_kernel(
    const unsigned short* __restrict__ A,    // o_bf [4096][1024]
    const unsigned short* __restrict__ W,    // wo_bf [1024][1024]
    const float* __restrict__ bias,
    float* __restrict__ out)
{
  __shared__ unsigned short As[128 * 32];
  __shared__ unsigned short Bs[128 * 32];
  const int tid = threadIdx.x;
  const int w = tid >> 6, l = tid & 63;
  const int lm = l & 15, quad = l >> 4;
  const int m0 = blockIdx.y * 128;
  const int n0 = blockIdx.x * 128;
  const int wm = (w >> 1) * 64, wn = (w & 1) * 64;

  const f32x4 fzero = {0.f, 0.f, 0.f, 0.f};
  f32x4 acc[4][4];
#pragma unroll
  for (int i = 0; i < 4; ++i)
#pragma unroll
    for (int j = 0; j < 4; ++j) acc[i][j] = fzero;

  const int rowS = w * 16 + lm;
  for (int k0 = 0; k0 < 1024; k0 += 32) {
    __syncthreads();
#pragma unroll
    for (int p = 0; p < 2; ++p) {
      const int row = rowS + p * 64;
      async16(A + (size_t)(m0 + row) * 1024 + k0 + quad * 8,
              As + (size_t)(w * 64 + p * 256) * 8);
      async16(W + (size_t)(n0 + row) * 1024 + k0 + quad * 8,
              Bs + (size_t)(w * 64 + p * 256) * 8);
    }
    __syncthreads();
    bf16x8 af[4], bfc[4];
#pragma unroll
    for (int i = 0; i < 4; ++i)
      af[i] = *(const bf16x8*)(As + (size_t)((((w >> 1) * 4 + i) * 64 + l)) * 8);
#pragma unroll
    for (int j = 0; j < 4; ++j)
      bfc[j] = *(const bf16x8*)(Bs + (size_t)((((w & 1) * 4 + j) * 64 + l)) * 8);
#pragma unroll
    for (int i = 0; i < 4; ++i)
#pragma unroll
      for (int j = 0; j < 4; ++j)
        acc[i][j] = __builtin_amdgcn_mfma_f32_16x16x32_bf16(af[i], bfc[j], acc[i][j], 0, 0, 0);
  }

#pragma unroll
  for (int i = 0; i < 4; ++i) {
#pragma unroll
    for (int j = 0; j < 4; ++j) {
      const int n = n0 + wn + j * 16 + lm;
      const float bval = bias[n];
#pragma unroll
      for (int r = 0; r < 4; ++r) {
        const int m = m0 + wm + i * 16 + quad * 4 + r;
        out[(size_t)m * 1024 + n] = acc[i][j][r] + bval;
      }
    }
  }
}

// ---------------- host launch ----------------
extern "C" void kernel_launch(void* const* d_in, const int* in_sizes, int n_in,
                              void* d_out, int out_size, void* d_ws, size_t ws_size,
                              hipStream_t stream) {
  (void)in_sizes; (void)n_in; (void)out_size; (void)ws_size;
  const float* x  = (const float*)d_in[0];
  const float* cp = (const float*)d_in[1];
  const float* sp = (const float*)d_in[2];
  const float* wq = (const float*)d_in[3];
  const float* bq = (const float*)d_in[4];
  const float* wk = (const float*)d_in[5];
  const float* bk = (const float*)d_in[6];
  const float* wv = (const float*)d_in[7];
  const float* bv = (const float*)d_in[8];
  const float* wo = (const float*)d_in[9];
  const float* bo = (const float*)d_in[10];
  float* out = (float*)d_out;

  unsigned short* xbf  = (unsigned short*)d_ws;          // 4M shorts
  unsigned short* wqkv = xbf  + (size_t)4 * 1024 * 1024; // 3M
  unsigned short* wobf = wqkv + (size_t)3 * 1024 * 1024; // 1M
  unsigned short* qbf  = wobf + (size_t)1 * 1024 * 1024; // 4M (bh,s,d)
  unsigned short* kbf  = qbf  + (size_t)4 * 1024 * 1024; // 4M (tiled frag-major)
  unsigned short* vbf  = kbf  + (size_t)4 * 1024 * 1024; // 4M (V^T tiled)
  unsigned short* obf  = vbf  + (size_t)4 * 1024 * 1024; // 4M (b,s,h*64+d)

  hipLaunchKernelGGL(cast_kernel, dim3(4096), dim3(256), 0, stream, x, xbf, 1048576);
  hipLaunchKernelGGL(cast_w_kernel, dim3(4096), dim3(256), 0, stream,
                     wq, wk, wv, wo, wqkv, wobf);

  hipLaunchKernelGGL(qkv_gemm_kernel, dim3(24, 32), dim3(256), 0, stream,
                     xbf, wqkv, bq, bk, bv, cp, sp, qbf, kbf, vbf);
  hipLaunchKernelGGL(flash_kernel, dim3(32, 16), dim3(512), 0, stream,
                     qbf, kbf, vbf, obf);
  hipLaunchKernelGGL(oproj_gemm_kernel, dim3(8, 32), dim3(256), 0, stream,
                     obf, wobf, bo, out);
}

// Round 5
// 236.958 us; speedup vs baseline: 1.8605x; 1.0144x over previous
//
#include <hip/hip_runtime.h>
#include <stdint.h>
#include <stddef.h>

// ============================================================================
// MHA block on gfx950, bf16 MFMA pipeline.  B=2,S=2048,D=1024,H=16,hd=64.
// R5 changes vs R4 (qkv 65.9us, MfmaUtil 14.5%, latency-bound on barrier
// drains; oproj grid was 256 blocks = 1 block/CU):
//  - qkv_gemm: BK 32->64 (16 K-iters, 32 MFMA/iter/wave, 32KB LDS) -- halves
//    the number of vmcnt(0) barrier drains per block.
//  - oproj_gemm: 64x128 tiles (512 blocks = 2/CU) + BK=64, acc[4][2]/wave.
//  - flash untouched (isolate; its counters land next round).
// MFMA layouts (verified m89/m91/m120):
//   A-frag: A[m=lane&15][k=(lane>>4)*8+j]  (16B/lane contiguous)
//   B-frag: B[k=(lane>>4)*8+j][n=lane&15] == row-major read of B^T tile
//   C/D:    col=lane&15, row=(lane>>4)*4+reg
// GEMM LDS fragment-major (BK=64): chunk(row,kc) = (row>>4)*128 + kc*16
//   + (row&15), kc = k>>3 in 0..7.  Wave stage base = (w+4*(q&1))*128
//   + 64*(q>>1), lane at +l -> wave-uniform base + lane*16B for
//   global_load_lds; frag reads are lane-contiguous 1KB blocks.
// ============================================================================

typedef __bf16 bf16x8 __attribute__((ext_vector_type(8)));
typedef float  f32x4  __attribute__((ext_vector_type(4)));

__device__ __forceinline__ unsigned short f2b(float f) {
  union { float f; uint32_t u; } v; v.f = f;
  uint32_t u = v.u;
  return (unsigned short)((u + 0x7FFFu + ((u >> 16) & 1u)) >> 16);  // RNE
}

__device__ __forceinline__ void async16(const void* g, void* l) {
  __builtin_amdgcn_global_load_lds(
      (const __attribute__((address_space(1))) void*)g,
      (__attribute__((address_space(3))) void*)l, 16, 0, 0);
}

// ---------------- cast x f32 -> bf16 ----------------
__global__ void cast_kernel(const float* __restrict__ in,
                            unsigned short* __restrict__ out, int n4) {
  int i = blockIdx.x * blockDim.x + threadIdx.x;
  if (i >= n4) return;
  float4 v = ((const float4*)in)[i];
  ushort4 o;
  o.x = f2b(v.x); o.y = f2b(v.y); o.z = f2b(v.z); o.w = f2b(v.w);
  ((ushort4*)out)[i] = o;
}

// ---------------- cast all 4 weight matrices in one launch ----------------
__global__ void cast_w_kernel(const float* __restrict__ wq, const float* __restrict__ wk,
                              const float* __restrict__ wv, const float* __restrict__ wo,
                              unsigned short* __restrict__ wqkv,
                              unsigned short* __restrict__ wobf) {
  int i = blockIdx.x * blockDim.x + threadIdx.x;   // 0 .. 4*2^18-1
  const int sel = i >> 18, k = i & ((1 << 18) - 1);
  const float* src = (sel == 0) ? wq : (sel == 1) ? wk : (sel == 2) ? wv : wo;
  float4 v = ((const float4*)src)[k];
  ushort4 o;
  o.x = f2b(v.x); o.y = f2b(v.y); o.z = f2b(v.z); o.w = f2b(v.w);
  if (sel < 3) ((ushort4*)wqkv)[(size_t)sel * 262144 + k] = o;
  else         ((ushort4*)wobf)[k] = o;
}

// ---------------- fused QKV projection GEMM (+bias, +RoPE on q/k) ----------
// C[4096,3072] = Xbf[4096,1024] @ Wqkv[3072,1024]^T, 128x128 tiles, BK=64.
// Output layouts:
//   q: [bh][2048][64] row-major (RoPE'd)
//   k: tiled frag-major: [bh][st=32][ chunk L = (d>>3)*64 + (s&63) ][8 of d]
//   v: V^T tiled frag-major: [bh][st=32][ chunk L = ((s&63)>>3)*64 + d ][8 of s]
__global__ __launch_bounds__(256) void qkv_gemm_kernel(
    const unsigned short* __restrict__ A,    // x_bf [4096][1024]
    const unsigned short* __restrict__ W,    // wqkv [3072][1024]
    const float* __restrict__ biasq, const float* __restrict__ biask,
    const float* __restrict__ biasv,
    const float* __restrict__ cp, const float* __restrict__ sp,  // [2048][32]
    unsigned short* __restrict__ qo,
    unsigned short* __restrict__ ko,
    unsigned short* __restrict__ vo)
{
  __shared__ unsigned short As[128 * 64];    // 16 KB
  __shared__ unsigned short Bs[128 * 64];    // 16 KB
  const int tid  = threadIdx.x;
  const int w    = tid >> 6, l = tid & 63;
  const int lm   = l & 15,  quad = l >> 4;
  const int nblk = blockIdx.x;               // 0..23
  const int m0   = blockIdx.y * 128;
  const int n0g  = nblk * 128;
  const int wm   = (w >> 1) * 64, wn = (w & 1) * 64;

  const f32x4 fzero = {0.f, 0.f, 0.f, 0.f};
  f32x4 acc[4][4];
#pragma unroll
  for (int i = 0; i < 4; ++i)
#pragma unroll
    for (int j = 0; j < 4; ++j) acc[i][j] = fzero;

  for (int k0 = 0; k0 < 1024; k0 += 64) {
    __syncthreads();                         // prev iter's ds_reads done
#pragma unroll
    for (int q = 0; q < 4; ++q) {
      const int row = w * 16 + lm + (q & 1) * 64;
      const int kc  = quad + (q >> 1) * 4;
      const size_t ldsb = ((size_t)(w + 4 * (q & 1)) * 128 + 64 * (q >> 1)) * 8;
      async16(A + (size_t)(m0 + row) * 1024 + k0 + kc * 8, As + ldsb);
      async16(W + (size_t)(n0g + row) * 1024 + k0 + kc * 8, Bs + ldsb);
    }
    __syncthreads();                         // drains vmcnt -> tile in LDS
#pragma unroll
    for (int kk = 0; kk < 2; ++kk) {
      bf16x8 af[4], bfc[4];
#pragma unroll
      for (int i = 0; i < 4; ++i)
        af[i] = *(const bf16x8*)(As + (size_t)((((w >> 1) * 4 + i) * 128 + kk * 64 + l)) * 8);
#pragma unroll
      for (int j = 0; j < 4; ++j)
        bfc[j] = *(const bf16x8*)(Bs + (size_t)((((w & 1) * 4 + j) * 128 + kk * 64 + l)) * 8);
#pragma unroll
      for (int i = 0; i < 4; ++i)
#pragma unroll
        for (int j = 0; j < 4; ++j)
          acc[i][j] = __builtin_amdgcn_mfma_f32_16x16x32_bf16(af[i], bfc[j], acc[i][j], 0, 0, 0);
    }
  }

  const int which = nblk >> 3;               // 0=q 1=k 2=v
  const int n0    = (nblk & 7) * 128;
  const float* bias = (which == 0) ? biasq : (which == 1) ? biask : biasv;
#pragma unroll
  for (int i = 0; i < 4; ++i) {
#pragma unroll
    for (int j = 0; j < 4; ++j) {
      const int n = n0 + wn + j * 16 + lm;
      const float bval = bias[n];
      const int h = n >> 6, d = n & 63;
      float vals[4];
#pragma unroll
      for (int r = 0; r < 4; ++r) {
        const int m = m0 + wm + i * 16 + quad * 4 + r;
        const int srow = m & 2047;
        float val = acc[i][j][r] + bval;
        if (which != 2) {
          const float c  = cp[srow * 32 + (d >> 1)];
          const float sn = sp[srow * 32 + (d >> 1)];
          const float part = __shfl_xor(val, 1, 64);
          val = (d & 1) ? (part * sn + val * c) : (val * c - part * sn);
        }
        vals[r] = val;
      }
      const int mbase = m0 + wm + i * 16 + quad * 4;   // 4 consecutive s
      const int b = mbase >> 11, s0 = mbase & 2047;
      const int bh = (b << 4) + h;
      if (which == 0) {
#pragma unroll
        for (int r = 0; r < 4; ++r)
          qo[((size_t)bh * 2048 + s0 + r) * 64 + d] = f2b(vals[r]);
      } else if (which == 1) {
        // tiled: base = (bh*32 + s>>6)*4096 + ((d>>3)*64 + (s&63))*8 + (d&7)
#pragma unroll
        for (int r = 0; r < 4; ++r) {
          const int s = s0 + r;
          ko[((size_t)bh * 32 + (s >> 6)) * 4096 +
             (size_t)(((d >> 3) * 64 + (s & 63))) * 8 + (d & 7)] = f2b(vals[r]);
        }
      } else {
        // V^T tiled, 4 consecutive s -> one uint2 (8B) store
        uint32_t w0 = (uint32_t)f2b(vals[0]) | ((uint32_t)f2b(vals[1]) << 16);
        uint32_t w1 = (uint32_t)f2b(vals[2]) | ((uint32_t)f2b(vals[3]) << 16);
        uint2 pk; pk.x = w0; pk.y = w1;
        *(uint2*)(vo + ((size_t)bh * 32 + (s0 >> 6)) * 4096 +
                  (size_t)((((s0 & 63) >> 3) * 64 + d)) * 8 + (s0 & 7)) = pk;
      }
    }
  }
}

// ---------------- flash attention ----------------
// grid (bh=32, 16); block 512 thr = 8 waves; wave w owns q-rows w*16..w*16+15.
// S^T = K*Q^T formulation: t in-lane, m = lane&15.
__global__ __launch_bounds__(512, 4) void flash_kernel(
    const unsigned short* __restrict__ Q,    // [32][2048][64] row-major
    const unsigned short* __restrict__ K,    // tiled frag-major (see qkv)
    const unsigned short* __restrict__ VT,   // V^T tiled frag-major
    unsigned short* __restrict__ O)          // [2][2048][1024]
{
  constexpr int PSTRIDE = 72;                // Ps row stride (shorts)
  __shared__ unsigned short Ks[4096];        // 64x64 tile, chunk L = c*64 + t
  __shared__ unsigned short Vs[4096];        // V^T tile, chunk L = ct*64 + d
  __shared__ unsigned short Ps[128 * PSTRIDE];
  const int tid = threadIdx.x;
  const int w = tid >> 6, l = tid & 63, lm = l & 15, quad = l >> 4;
  const int bh = blockIdx.x, qb = 15 - blockIdx.y;   // heavy q-blocks first
  const int mrow_g = qb * 128 + w * 16 + lm;         // this lane's softmax row

  // Q fragment to registers: lane reads row (qb*128+w*16+lm), 8 d at quad*8
  const size_t qbase = ((size_t)bh * 2048 + (size_t)qb * 128) * 64;
  bf16x8 aq[2];
#pragma unroll
  for (int kc = 0; kc < 2; ++kc)
    aq[kc] = *(const bf16x8*)(Q + qbase + (size_t)(w * 16 + lm) * 64 + kc * 32 + quad * 8);

  const f32x4 fzero = {0.f, 0.f, 0.f, 0.f};
  f32x4 Oacc[4];
#pragma unroll
  for (int jo = 0; jo < 4; ++jo) Oacc[jo] = fzero;
  float m_i = -1e30f, l_i = 0.f;

  const int nkv = 2 * qb + 2;
  for (int kt = 0; kt < nkv; ++kt) {
    __syncthreads();                         // prev iter done reading Ks/Vs
    {
      const size_t tbase = ((size_t)bh * 32 + kt) * 4096;
      async16(K  + tbase + (size_t)tid * 8, Ks + (size_t)w * 512);
      async16(VT + tbase + (size_t)tid * 8, Vs + (size_t)w * 512);
    }
    __syncthreads();                         // tiles in LDS

    // S^T = K * Q^T : Sc[tb] holds t = tb*16+quad*4+r (rows), m = lm (col)
    f32x4 Sc[4];
#pragma unroll
    for (int tb = 0; tb < 4; ++tb) Sc[tb] = fzero;
#pragma unroll
    for (int kc = 0; kc < 2; ++kc) {
      bf16x8 ak[4];
#pragma unroll
      for (int tb = 0; tb < 4; ++tb)
        ak[tb] = *(const bf16x8*)(Ks + (size_t)(((kc * 4 + quad) * 64 + tb * 16 + lm)) * 8);
#pragma unroll
      for (int tb = 0; tb < 4; ++tb)
        Sc[tb] = __builtin_amdgcn_mfma_f32_16x16x32_bf16(ak[tb], aq[kc], Sc[tb], 0, 0, 0);
    }

    // scale + causal mask.  Mask needed iff tile's max t (kt*64+63) exceeds
    // this wave's MIN row (qb*128 + w*16).
    const bool needmask = (kt * 64 + 63 > qb * 128 + w * 16);
    const int  mrel = mrow_g - kt * 64;      // mask t-index > mrel
    float mx = -1e30f;
#pragma unroll
    for (int tb = 0; tb < 4; ++tb) {
#pragma unroll
      for (int r = 0; r < 4; ++r) {
        float s = Sc[tb][r] * 0.125f;        // 1/sqrt(64)
        if (needmask && (tb * 16 + quad * 4 + r > mrel)) s = -1e30f;
        Sc[tb][r] = s;
        mx = fmaxf(mx, s);
      }
    }
    mx = fmaxf(mx, __shfl_xor(mx, 16, 64));
    mx = fmaxf(mx, __shfl_xor(mx, 32, 64));
    const float mnew  = fmaxf(m_i, mx);
    const float alpha = __expf(m_i - mnew);
    m_i = mnew;

    // exp, pack 4 consecutive t -> b64 write into Ps[m][t]
    float ps = 0.f;
#pragma unroll
    for (int tb = 0; tb < 4; ++tb) {
      float p0 = __expf(Sc[tb][0] - mnew), p1 = __expf(Sc[tb][1] - mnew);
      float p2 = __expf(Sc[tb][2] - mnew), p3 = __expf(Sc[tb][3] - mnew);
      ps += (p0 + p1) + (p2 + p3);
      uint2 pk;
      pk.x = (uint32_t)f2b(p0) | ((uint32_t)f2b(p1) << 16);
      pk.y = (uint32_t)f2b(p2) | ((uint32_t)f2b(p3) << 16);
      *(uint2*)(Ps + (size_t)(w * 16 + lm) * PSTRIDE + tb * 16 + quad * 4) = pk;
    }
    ps += __shfl_xor(ps, 16, 64);
    ps += __shfl_xor(ps, 32, 64);
    l_i = l_i * alpha + ps;

    // rescale Oacc: alpha lives per m=lm; O rows are quad*4+r -> shuffle
    float af4[4];
#pragma unroll
    for (int r = 0; r < 4; ++r) af4[r] = __shfl(alpha, quad * 4 + r, 64);
#pragma unroll
    for (int jo = 0; jo < 4; ++jo)
#pragma unroll
      for (int r = 0; r < 4; ++r) Oacc[jo][r] *= af4[r];

    // O += P V  (wave-private Ps rows; lgkmcnt orders write->read in-wave)
#pragma unroll
    for (int kc = 0; kc < 2; ++kc) {
      bf16x8 ap = *(const bf16x8*)(Ps + (size_t)(w * 16 + lm) * PSTRIDE + kc * 32 + quad * 8);
      bf16x8 bv[4];
#pragma unroll
      for (int jo = 0; jo < 4; ++jo)
        bv[jo] = *(const bf16x8*)(Vs + (size_t)(((kc * 4 + quad) * 64 + jo * 16 + lm)) * 8);
#pragma unroll
      for (int jo = 0; jo < 4; ++jo)
        Oacc[jo] = __builtin_amdgcn_mfma_f32_16x16x32_bf16(ap, bv[jo], Oacc[jo], 0, 0, 0);
    }
  }

  // epilogue: normalize, write o_bf (b, s, h*64+d)
  float lf[4];
#pragma unroll
  for (int r = 0; r < 4; ++r) lf[r] = 1.0f / __shfl(l_i, quad * 4 + r, 64);
  const int b = bh >> 4, h = bh & 15;
#pragma unroll
  for (int jo = 0; jo < 4; ++jo)
#pragma unroll
    for (int r = 0; r < 4; ++r) {
      const int s   = qb * 128 + w * 16 + quad * 4 + r;
      const int col = h * 64 + jo * 16 + lm;
      O[((size_t)b * 2048 + s) * 1024 + col] = f2b(Oacc[jo][r] * lf[r]);
    }
}

// ---------------- output projection GEMM ----------------
// out[4096,1024] = Obf[4096,1024] @ Wo[1024,1024]^T + bias (fp32 out).
// 64x128 tiles, BK=64, 512 blocks (2/CU).  Wave w covers cols w*32..w*32+31.
__global__ __launch_bounds__(256) void oproj_gemm_kernel(
    const unsigned short* __restrict__ A,    // o_bf [4096][1024]
    const unsigned short* __restrict__ W,    // wo_bf [1024][1024]
    const float* __restrict__ bias,
    float* __restrict__ out)
{
  __shared__ unsigned short As[64 * 64];     // 8 KB
  __shared__ unsigned short Bs[128 * 64];    // 16 KB
  const int tid = threadIdx.x;
  const int w = tid >> 6, l = tid & 63;
  const int lm = l & 15, quad = l >> 4;
  const int m0 = blockIdx.y * 64;
  const int n0 = blockIdx.x * 128;

  const f32x4 fzero = {0.f, 0.f, 0.f, 0.f};
  f32x4 acc[4][2];
#pragma unroll
  for (int i = 0; i < 4; ++i)
#pragma unroll
    for (int j = 0; j < 2; ++j) acc[i][j] = fzero;

  for (int k0 = 0; k0 < 1024; k0 += 64) {
    __syncthreads();
    // A: 64 rows x 8 kc = 512 chunks; 2 per thread
#pragma unroll
    for (int q = 0; q < 2; ++q) {
      const int row = w * 16 + lm;
      const int kc  = quad + 4 * q;
      async16(A + (size_t)(m0 + row) * 1024 + k0 + kc * 8,
              As + ((size_t)w * 128 + 64 * q) * 8);
    }
    // B: 128 rows x 8 kc = 1024 chunks; 4 per thread
#pragma unroll
    for (int q = 0; q < 4; ++q) {
      const int row = w * 16 + lm + (q & 1) * 64;
      const int kc  = quad + 4 * (q >> 1);
      async16(W + (size_t)(n0 + row) * 1024 + k0 + kc * 8,
              Bs + ((size_t)(w + 4 * (q & 1)) * 128 + 64 * (q >> 1)) * 8);
    }
    __syncthreads();
#pragma unroll
    for (int kk = 0; kk < 2; ++kk) {
      bf16x8 af[4], bfc[2];
#pragma unroll
      for (int i = 0; i < 4; ++i)
        af[i] = *(const bf16x8*)(As + (size_t)((i * 128 + kk * 64 + l)) * 8);
#pragma unroll
      for (int j = 0; j < 2; ++j)
        bfc[j] = *(const bf16x8*)(Bs + (size_t)(((w * 2 + j) * 128 + kk * 64 + l)) * 8);
#pragma unroll
      for (int i = 0; i < 4; ++i)
#pragma unroll
        for (int j = 0; j < 2; ++j)
          acc[i][j] = __builtin_amdgcn_mfma_f32_16x16x32_bf16(af[i], bfc[j], acc[i][j], 0, 0, 0);
    }
  }

#pragma unroll
  for (int i = 0; i < 4; ++i) {
#pragma unroll
    for (int j = 0; j < 2; ++j) {
      const int n = n0 + w * 32 + j * 16 + lm;
      const float bval = bias[n];
#pragma unroll
      for (int r = 0; r < 4; ++r) {
        const int m = m0 + i * 16 + quad * 4 + r;
        out[(size_t)m * 1024 + n] = acc[i][j][r] + bval;
      }
    }
  }
}

// ---------------- host launch ----------------
extern "C" void kernel_launch(void* const* d_in, const int* in_sizes, int n_in,
                              void* d_out, int out_size, void* d_ws, size_t ws_size,
                              hipStream_t stream) {
  (void)in_sizes; (void)n_in; (void)out_size; (void)ws_size;
  const float* x  = (const float*)d_in[0];
  const float* cp = (const float*)d_in[1];
  const float* sp = (const float*)d_in[2];
  const float* wq = (const float*)d_in[3];
  const float* bq = (const float*)d_in[4];
  const float* wk = (const float*)d_in[5];
  const float* bk = (const float*)d_in[6];
  const float* wv = (const float*)d_in[7];
  const float* bv = (const float*)d_in[8];
  const float* wo = (const float*)d_in[9];
  const float* bo = (const float*)d_in[10];
  float* out = (float*)d_out;

  unsigned short* xbf  = (unsigned short*)d_ws;          // 4M shorts
  unsigned short* wqkv = xbf  + (size_t)4 * 1024 * 1024; // 3M
  unsigned short* wobf = wqkv + (size_t)3 * 1024 * 1024; // 1M
  unsigned short* qbf  = wobf + (size_t)1 * 1024 * 1024; // 4M (bh,s,d)
  unsigned short* kbf  = qbf  + (size_t)4 * 1024 * 1024; // 4M (tiled frag-major)
  unsigned short* vbf  = kbf  + (size_t)4 * 1024 * 1024; // 4M (V^T tiled)
  unsigned short* obf  = vbf  + (size_t)4 * 1024 * 1024; // 4M (b,s,h*64+d)

  hipLaunchKernelGGL(cast_kernel, dim3(4096), dim3(256), 0, stream, x, xbf, 1048576);
  hipLaunchKernelGGL(cast_w_kernel, dim3(4096), dim3(256), 0, stream,
                     wq, wk, wv, wo, wqkv, wobf);

  hipLaunchKernelGGL(qkv_gemm_kernel, dim3(24, 32), dim3(256), 0, stream,
                     xbf, wqkv, bq, bk, bv, cp, sp, qbf, kbf, vbf);
  hipLaunchKernelGGL(flash_kernel, dim3(32, 16), dim3(512), 0, stream,
                     qbf, kbf, vbf, obf);
  hipLaunchKernelGGL(oproj_gemm_kernel, dim3(8, 64), dim3(256), 0, stream,
                     obf, wobf, bo, out);
}